// Round 1
// baseline (616.813 us; speedup 1.0000x reference)
//
#include <hip/hip_runtime.h>
#include <math.h>

#define BS 4
#define TSEG 16
#define CC 64
#define DD 64
#define NN 4096
#define KK 32
#define HH 64
#define D5 320

__device__ __forceinline__ float sigm(float x){ return 1.0f/(1.0f+expf(-x)); }

// ---------------------------------------------------------------------------
// Kernel 1: pre-scan modulation. One wave per node (4 nodes / 256-thr block).
// Phase 1: lane = h. fc1 matvec (320x64) for all 4 batches, fc2 -> gates.
// Phase 2: lane = d. trace norms, eff_prim, eff_key, routing dots.
// ---------------------------------------------------------------------------
__global__ __launch_bounds__(256) void k_pre(
    const float* __restrict__ h_prev,
    const float* __restrict__ pm0,
    const float* __restrict__ trp,
    const float* __restrict__ trk,
    const float* __restrict__ prim,
    const float* __restrict__ keyp,
    const float* __restrict__ dlog,
    const float* __restrict__ fc1w,
    const float* __restrict__ fc1b,
    const float* __restrict__ fc2w,
    const float* __restrict__ fc2b,
    const float* __restrict__ mll,
    const int*  __restrict__ conn,
    float* __restrict__ ws_h,
    float* __restrict__ ws_ep,
    float* __restrict__ ws_rt,
    float* __restrict__ ws_ed)
{
    // mod input staged transposed: mod2[node][d][b]  (float4 per d)
    __shared__ float mod2[4][D5][4];
    __shared__ int   cn_s[4][KK];
    const int wid  = threadIdx.x >> 6;
    const int lane = threadIdx.x & 63;
    const int n    = (blockIdx.x << 2) + wid;

    #pragma unroll
    for (int b = 0; b < BS; b++) {
        mod2[wid][lane      ][b] = h_prev[((size_t)b*NN + n)*DD + lane];
        mod2[wid][64  + lane][b] = trp  [((size_t)b*NN + n)*DD + lane];
        mod2[wid][128 + lane][b] = trk  [((size_t)b*NN + n)*DD + lane];
    }
    {
        const float pv = prim[(size_t)n*DD + lane];
        const float kv = keyp[(size_t)n*DD + lane];
        #pragma unroll
        for (int b = 0; b < BS; b++) {
            mod2[wid][192 + lane][b] = pv;
            mod2[wid][256 + lane][b] = kv;
        }
    }
    if (lane < KK) cn_s[wid][lane] = conn[(size_t)n*KK + lane];
    __syncthreads();

    // fc1: acc[b] = sum_d mod[b][d] * fc1w[n][d][lane]
    float acc[4] = {0.f, 0.f, 0.f, 0.f};
    const float* wp = fc1w + (size_t)n * D5 * HH + lane;
    #pragma unroll 8
    for (int d = 0; d < D5; d++) {
        const float  w  = wp[(size_t)d * HH];
        const float4 mv = *(const float4*)(&mod2[wid][d][0]);
        acc[0] = fmaf(mv.x, w, acc[0]);
        acc[1] = fmaf(mv.y, w, acc[1]);
        acc[2] = fmaf(mv.z, w, acc[2]);
        acc[3] = fmaf(mv.w, w, acc[3]);
    }
    const float b1 = fc1b[(size_t)n*HH + lane];
    float x[4];
    #pragma unroll
    for (int b = 0; b < BS; b++) x[b] = tanhf(acc[b] + b1);

    // fc2: out3[b][o] = sum_h x[b][h]*fc2w[n][h][o] + fc2b[n][o]
    const float f0 = fc2w[(size_t)n*HH*3 + lane*3 + 0];
    const float f1 = fc2w[(size_t)n*HH*3 + lane*3 + 1];
    const float f2 = fc2w[(size_t)n*HH*3 + lane*3 + 2];
    float po[4][3];
    #pragma unroll
    for (int b = 0; b < BS; b++) { po[b][0]=x[b]*f0; po[b][1]=x[b]*f1; po[b][2]=x[b]*f2; }
    #pragma unroll
    for (int m = 1; m < 64; m <<= 1) {
        #pragma unroll
        for (int b = 0; b < BS; b++) {
            #pragma unroll
            for (int o = 0; o < 3; o++) po[b][o] += __shfl_xor(po[b][o], m, 64);
        }
    }
    const float c0 = fc2b[(size_t)n*3+0];
    const float c1 = fc2b[(size_t)n*3+1];
    const float c2 = fc2b[(size_t)n*3+2];
    const float dl  = dlog[n];
    const float mlr = sigm(mll[0]);
    float gp[4], gk[4], ed[4];
    #pragma unroll
    for (int b = 0; b < BS; b++) {
        gp[b] = tanhf(po[b][0] + c0);
        gk[b] = tanhf(po[b][1] + c1);
        ed[b] = sigm(dl + po[b][2] + c2);
    }
    {
        const float edsel = (lane==0)?ed[0]:(lane==1)?ed[1]:(lane==2)?ed[2]:ed[3];
        if (lane < 4) ws_ed[(size_t)lane*NN + n] = edsel;
    }

    // ---- phase 2: lane = d ----
    const int d = lane;
    const float4 hpv = *(const float4*)(&mod2[wid][d      ][0]);
    const float4 tpv = *(const float4*)(&mod2[wid][64  + d][0]);
    const float4 tkv = *(const float4*)(&mod2[wid][128 + d][0]);
    const float  pr  = mod2[wid][192 + d][0];
    const float  kp  = mod2[wid][256 + d][0];
    float hp[4] = {hpv.x, hpv.y, hpv.z, hpv.w};
    float tp[4] = {tpv.x, tpv.y, tpv.z, tpv.w};
    float tk[4] = {tkv.x, tkv.y, tkv.z, tkv.w};

    float s2[8];
    #pragma unroll
    for (int b = 0; b < BS; b++) { s2[b] = tp[b]*tp[b]; s2[4+b] = tk[b]*tk[b]; }
    #pragma unroll
    for (int m = 1; m < 64; m <<= 1) {
        #pragma unroll
        for (int i = 0; i < 8; i++) s2[i] += __shfl_xor(s2[i], m, 64);
    }
    float ep[4], ek[4];
    #pragma unroll
    for (int b = 0; b < BS; b++) {
        const float np = fmaxf(sqrtf(s2[b]),   1e-8f);
        const float nk = fmaxf(sqrtf(s2[4+b]), 1e-8f);
        ep[b] = pr + mlr*gp[b]*(tp[b]/np);
        ek[b] = kp + mlr*gk[b]*(tk[b]/nk);
    }
    #pragma unroll
    for (int b = 0; b < BS; b++) {
        ws_ep[((size_t)b*NN + n)*DD + d] = ep[b];
        ws_h [((size_t)b*NN + n)*DD + d] = hp[b];
    }
    // routing[b][n][k] = sigmoid(sum_d ek[b][d] * pm0[b][conn[n][k]][d])
    #pragma unroll 4
    for (int k = 0; k < KK; k++) {
        const int cn = cn_s[wid][k];
        float rr[4];
        #pragma unroll
        for (int b = 0; b < BS; b++) rr[b] = ek[b]*pm0[((size_t)b*NN + cn)*DD + d];
        #pragma unroll
        for (int m = 1; m < 64; m <<= 1) {
            #pragma unroll
            for (int b = 0; b < BS; b++) rr[b] += __shfl_xor(rr[b], m, 64);
        }
        const float rsel = (lane==0)?rr[0]:(lane==1)?rr[1]:(lane==2)?rr[2]:rr[3];
        if (lane < 4) ws_rt[((size_t)lane*NN + n)*KK + k] = sigm(rsel);
    }
}

// ---------------------------------------------------------------------------
// Kernel 2: one scan step. Block = node, wave = batch, lane = d.
// ---------------------------------------------------------------------------
__global__ __launch_bounds__(256) void k_step(
    const float* __restrict__ pm_in,
    float* __restrict__ pm_out,
    float* __restrict__ ws_h,
    const float* __restrict__ ws_ep,
    const float* __restrict__ ws_rt,
    const float* __restrict__ ws_ed,
    const float* __restrict__ bw,
    const float* __restrict__ gw,
    const int*  __restrict__ conn,
    const float* __restrict__ cc,
    float* __restrict__ out,
    const int s)
{
    __shared__ float bw_s[2048];   // [j][kk][d] = [k][d]
    __shared__ float gw_s[256];    // [p][d]
    __shared__ float rt_s[4][KK];
    __shared__ int   cn_s[KK];
    const int n   = blockIdx.x;
    const int tid = threadIdx.x;
    {
        const float4* src = (const float4*)(bw + (size_t)n*2048);
        float4* dst = (float4*)bw_s;
        dst[tid]       = src[tid];
        dst[tid + 256] = src[tid + 256];
        if (tid < 64) ((float4*)gw_s)[tid] = ((const float4*)(gw + (size_t)n*256))[tid];
        if (tid < KK) cn_s[tid] = conn[(size_t)n*KK + tid];
        if (tid < 128) rt_s[tid>>5][tid&31] =
            ws_rt[((size_t)(tid>>5)*NN + n)*KK + (tid & 31)];
    }
    __syncthreads();

    const int b = tid >> 6, d = tid & 63;
    const size_t bn = ((size_t)b*NN + n)*DD + d;

    float bs0=0.f, bs1=0.f, bs2=0.f, bs3=0.f;
    #pragma unroll
    for (int k = 0; k < KK; k++) {
        const int   cn = cn_s[k];
        const float nm = pm_in[((size_t)b*NN + cn)*DD + d];
        const float wg = rt_s[b][k] * nm;
        const float bv = bw_s[k*DD + d];
        if      (k <  8) bs0 = fmaf(wg, bv, bs0);
        else if (k < 16) bs1 = fmaf(wg, bv, bs1);
        else if (k < 24) bs2 = fmaf(wg, bv, bs2);
        else             bs3 = fmaf(wg, bv, bs3);
    }
    const float br0 = tanhf(bs0), br1 = tanhf(bs1), br2 = tanhf(bs2), br3 = tanhf(bs3);
    const float gs = br0*gw_s[d] + br1*gw_s[64+d] + br2*gw_s[128+d] + br3*gw_s[192+d];
    float recv = tanhf(gs);
    if (n < CC) recv += cc[(size_t)((b*TSEG + 4*s)*CC + n)*DD + d];

    const float edv = ws_ed[(size_t)b*NN + n];
    const float hn  = edv*ws_h[bn] + (1.0f - edv)*recv;
    ws_h[bn] = hn;
    const float pmv = tanhf(hn * ws_ep[bn]);
    pm_out[bn] = pmv;
    if (n < CC) {
        #pragma unroll
        for (int r = 0; r < 4; r++)
            out[(size_t)((b*TSEG + 4*s + r)*CC + n)*DD + d] = pmv;
    }
}

extern "C" void kernel_launch(void* const* d_in, const int* in_sizes, int n_in,
                              void* d_out, int out_size, void* d_ws, size_t ws_size,
                              hipStream_t stream) {
    const float* cc    = (const float*)d_in[0];
    const float* h_prev= (const float*)d_in[1];
    const float* pm0   = (const float*)d_in[2];
    const float* trp   = (const float*)d_in[3];
    const float* trk   = (const float*)d_in[4];
    const float* prim  = (const float*)d_in[5];
    const float* keyp  = (const float*)d_in[6];
    const float* dlog  = (const float*)d_in[7];
    const float* bw    = (const float*)d_in[8];
    const float* gw    = (const float*)d_in[9];
    const float* fc1w  = (const float*)d_in[10];
    const float* fc1b  = (const float*)d_in[11];
    const float* fc2w  = (const float*)d_in[12];
    const float* fc2b  = (const float*)d_in[13];
    const float* mll   = (const float*)d_in[14];
    const int*   conn  = (const int*)d_in[15];
    float* out = (float*)d_out;

    float* ws   = (float*)d_ws;
    const size_t BND = (size_t)BS*NN*DD;          // 1048576
    float* ws_h  = ws;
    float* ws_ep = ws + BND;
    float* msgA  = ws + 2*BND;
    float* msgB  = ws + 3*BND;
    float* ws_rt = ws + 4*BND;                    // BS*NN*KK = 524288
    float* ws_ed = ws + 4*BND + (size_t)BS*NN*KK; // BS*NN   = 16384

    k_pre<<<NN/4, 256, 0, stream>>>(h_prev, pm0, trp, trk, prim, keyp, dlog,
                                    fc1w, fc1b, fc2w, fc2b, mll, conn,
                                    ws_h, ws_ep, ws_rt, ws_ed);

    k_step<<<NN, 256, 0, stream>>>(pm0,  msgA, ws_h, ws_ep, ws_rt, ws_ed,
                                   bw, gw, conn, cc, out, 0);
    k_step<<<NN, 256, 0, stream>>>(msgA, msgB, ws_h, ws_ep, ws_rt, ws_ed,
                                   bw, gw, conn, cc, out, 1);
    k_step<<<NN, 256, 0, stream>>>(msgB, msgA, ws_h, ws_ep, ws_rt, ws_ed,
                                   bw, gw, conn, cc, out, 2);
    k_step<<<NN, 256, 0, stream>>>(msgA, msgB, ws_h, ws_ep, ws_rt, ws_ed,
                                   bw, gw, conn, cc, out, 3);
}